// Round 5
// baseline (716.022 us; speedup 1.0000x reference)
//
#include <hip/hip_runtime.h>
#include <hip/hip_bf16.h>
#include <cstdint>

#define BATCH 1024
#define NPRE  8192
#define NPOST 8192

typedef _Float16 half8  __attribute__((ext_vector_type(8)));
typedef _Float16 half4_t __attribute__((ext_vector_type(4)));
typedef float    float4_t __attribute__((ext_vector_type(4)));

__device__ constexpr float ALPHA_SYN = 0.8187307530779818f; // exp(-0.001/0.005)
__device__ constexpr float DT_C = 0.001f;

// ---------------------------------------------------------------- prep
__global__ __launch_bounds__(256) void prep_kernel(
    const float* __restrict__ spikes, const float* __restrict__ x_std,
    const float* __restrict__ I_syn,
    const float* __restrict__ log_tau_rec, const float* __restrict__ logit_U,
    _Float16* __restrict__ Ah, float* __restrict__ out)
{
    const float tau_rec   = expf(log_tau_rec[0]);
    const float alpha_rec = expf(-DT_C / tau_rec);
    const float U         = 1.0f / (1.0f + expf(-logit_U[0]));

    const size_t i = ((size_t)blockIdx.x * 256 + threadIdx.x) * 4;
    float4_t sp = *(const float4_t*)(spikes + i);
    float4_t xs = *(const float4_t*)(x_std + i);
    float4_t is = *(const float4_t*)(I_syn + i);
    float4_t xn, ipre;
    half4_t  a;
#pragma unroll
    for (int j = 0; j < 4; ++j) {
        float x1  = 1.0f - (1.0f - xs[j]) * alpha_rec;
        float av  = sp[j] * U * x1;
        a[j]      = (_Float16)av;
        float spc = fminf(fmaxf(sp[j], 0.0f), 1.0f);
        xn[j]     = x1 * (1.0f - U * spc);
        ipre[j]   = is[j] * ALPHA_SYN;
    }
    *(half4_t*)(Ah + i)                           = a;
    *(float4_t*)(out + (size_t)BATCH * NPOST + i) = xn;
    *(float4_t*)(out + i)                         = ipre;
}

// ---------------------------------------------------------------- transpose
__global__ __launch_bounds__(256) void transpose_kernel(
    const float* __restrict__ W, _Float16* __restrict__ Wt)
{
    __shared__ float tile[64][65];
    const int n0 = blockIdx.x * 64;
    const int k0 = blockIdx.y * 64;
    const int t  = threadIdx.x;
    const int rr = t >> 4;
    const int cc = t & 15;
#pragma unroll
    for (int it = 0; it < 4; ++it) {
        const int r = it * 16 + rr;
        float4_t v = *(const float4_t*)(W + (size_t)(k0 + r) * NPOST + n0 + cc * 4);
        tile[r][cc * 4 + 0] = v[0];
        tile[r][cc * 4 + 1] = v[1];
        tile[r][cc * 4 + 2] = v[2];
        tile[r][cc * 4 + 3] = v[3];
    }
    __syncthreads();
    const int n  = t >> 2;
    const int kc = (t & 3) * 16;
    half8 h0, h1;
#pragma unroll
    for (int j = 0; j < 8; ++j) h0[j] = (_Float16)tile[kc + j][n];
#pragma unroll
    for (int j = 0; j < 8; ++j) h1[j] = (_Float16)tile[kc + 8 + j][n];
    _Float16* dst = Wt + (size_t)(n0 + n) * NPRE + k0 + kc;
    *(half8*)(dst)     = h0;
    *(half8*)(dst + 8) = h1;
}

// ---------------------------------------------------------------- GEMM
// 256x256 tile, BK=32, 8 waves (2Mx4N, wave-tile 128x64), 2-buffer LDS (64 KB),
// stage(t+1) at top of tile t (full-tile prefetch window), ONE sync per tile,
// 64 MFMA/wave/barrier, r4-verified slot swizzle (0 conflicts), T5 setprio,
// T1 XCD map, atomic epilogue onto I_syn*alpha prefill.
#define BM 256
#define BN 256
#define BK 32
#define SPLITK 2
#define KSPAN (NPRE / SPLITK)   // 4096
#define NT (KSPAN / BK)         // 128 K-tiles

__device__ __forceinline__ void gload_lds16(const _Float16* g, _Float16* l) {
    __builtin_amdgcn_global_load_lds(
        (const __attribute__((address_space(1))) void*)g,
        (__attribute__((address_space(3))) void*)l, 16, 0, 0);
}

__global__ __launch_bounds__(512, 2) void gemm_kernel(
    const _Float16* __restrict__ Ah, const _Float16* __restrict__ Wt,
    const float* __restrict__ noise,
    const float* __restrict__ log_strength, float* __restrict__ out)
{
    __shared__ _Float16 As[2][BM * BK];   // 16 KB each
    __shared__ _Float16 Bs[2][BN * BK];

    const int tid  = threadIdx.x;
    const int lane = tid & 63;
    const int wid  = tid >> 6;    // 0..7
    const int wr   = wid >> 2;    // 0..1  rows wr*128
    const int wc   = wid & 3;     // 0..3  cols wc*64

    // T1: XCD-grouped decode (4 mblk x 2 split x 4 nblk per XCD)
    const int idx   = blockIdx.x;            // 0..255
    const int xcd   = idx & 7;
    const int rank  = idx >> 3;              // 0..31
    const int nblk  = xcd * 4 + (rank & 3);  // 0..31
    const int mblk  = (rank >> 2) & 3;       // 0..3
    const int split = rank >> 4;             // 0..1
    const int bm0   = mblk * BM;
    const int bn0   = nblk * BN;
    const int kbase = split * KSPAN;

    // ---- staging: round = 8 KB = 128 rows x 64B. thread t -> row 128r+(t>>2),
    // 16B piece (t&3). Swizzle (r4-verified, 0 conflicts): global piece
    // p = (t&3) ^ ((row>>1)&3); LDS dest stays linear (HW: base + lane*16).
    const int srow = tid >> 2;                       // 0..127
    const int sp   = (tid & 3) ^ ((srow >> 1) & 3);  // swizzled k-piece
    const _Float16* agb = Ah + (size_t)(bm0 + srow) * NPRE + kbase + sp * 8;
    const _Float16* bgb = Wt + (size_t)(bn0 + srow) * NPRE + kbase + sp * 8;
    const int ldsw = wid * 512;                      // wave-uniform base (halfs)

    // 4 gloads per tile: A rows 0-127, A rows 128-255, B rows 0-127, B rows 128-255
#define STAGE(b, t)                                                           \
    {                                                                         \
        const size_t kg = (size_t)(t) * BK;                                   \
        gload_lds16(agb + kg, &As[b][ldsw]);                                  \
        gload_lds16(agb + (size_t)128 * NPRE + kg, &As[b][4096 + ldsw]);      \
        gload_lds16(bgb + kg, &Bs[b][ldsw]);                                  \
        gload_lds16(bgb + (size_t)128 * NPRE + kg, &Bs[b][4096 + ldsw]);      \
    }

    // ---- fragment addressing (r4-verified): row*32 + (lq ^ ((l16>>1)&3))*8
    const int l16 = lane & 15;
    const int lq  = lane >> 4;
    const int fsw = (lq ^ ((l16 >> 1) & 3)) * 8;
    int offA0[4], offA1[4], offB[4];
#pragma unroll
    for (int m = 0; m < 4; ++m) {
        offA0[m] = (wr * 128 + m * 16 + l16) * 32 + fsw;
        offA1[m] = (wr * 128 + (4 + m) * 16 + l16) * 32 + fsw;
    }
#pragma unroll
    for (int n = 0; n < 4; ++n)
        offB[n] = (wc * 64 + n * 16 + l16) * 32 + fsw;

    float4_t acc[8][4];
#pragma unroll
    for (int m = 0; m < 8; ++m)
#pragma unroll
        for (int n = 0; n < 4; ++n) acc[m][n] = {0.f, 0.f, 0.f, 0.f};

    // ---- prologue: stage tile 0 into buf 0
    STAGE(0, 0);

    for (int t = 0; t < NT; ++t) {
        const int cb = t & 1;
        __syncthreads();   // drains vmcnt(0): tile t's stages landed;
                           // all waves done reading buf cb^1 (tile t-1)
        if (t + 1 < NT) STAGE(cb ^ 1, t + 1);   // full-tile prefetch window

        half8 bf[4], af[4];
#pragma unroll
        for (int n = 0; n < 4; ++n) bf[n] = *(const half8*)&Bs[cb][offB[n]];
#pragma unroll
        for (int m = 0; m < 4; ++m) af[m] = *(const half8*)&As[cb][offA0[m]];
        __builtin_amdgcn_s_setprio(1);
#pragma unroll
        for (int m = 0; m < 4; ++m)
#pragma unroll
            for (int n = 0; n < 4; ++n)
                acc[m][n] = __builtin_amdgcn_mfma_f32_16x16x32_f16(
                    af[m], bf[n], acc[m][n], 0, 0, 0);
        __builtin_amdgcn_s_setprio(0);

#pragma unroll
        for (int m = 0; m < 4; ++m) af[m] = *(const half8*)&As[cb][offA1[m]];
        __builtin_amdgcn_s_setprio(1);
#pragma unroll
        for (int m = 0; m < 4; ++m)
#pragma unroll
            for (int n = 0; n < 4; ++n)
                acc[4 + m][n] = __builtin_amdgcn_mfma_f32_16x16x32_f16(
                    af[m], bf[n], acc[4 + m][n], 0, 0, 0);
        __builtin_amdgcn_s_setprio(0);
    }

    // ---- epilogue: out += s*acc*(1+0.15*noise) (prefill = I_syn*alpha)
    const float s = expf(log_strength[0]);
    const int lq4 = lq * 4;
#pragma unroll
    for (int m = 0; m < 8; ++m) {
#pragma unroll
        for (int n = 0; n < 4; ++n) {
            const int col = bn0 + wc * 64 + n * 16 + l16;
#pragma unroll
            for (int r = 0; r < 4; ++r) {
                const int row = bm0 + wr * 128 + m * 16 + lq4 + r;
                const size_t o = (size_t)row * NPOST + col;
                const float v = acc[m][n][r] * s * (1.0f + noise[o] * 0.15f);
                unsafeAtomicAdd(&out[o], v);
            }
        }
    }
#undef STAGE
}

// ---------------------------------------------------------------- launch
extern "C" void kernel_launch(void* const* d_in, const int* in_sizes, int n_in,
                              void* d_out, int out_size, void* d_ws, size_t ws_size,
                              hipStream_t stream) {
    const float* spikes       = (const float*)d_in[0];
    const float* I_syn        = (const float*)d_in[1];
    const float* x_std        = (const float*)d_in[2];
    const float* noise        = (const float*)d_in[3];
    const float* Wnm          = (const float*)d_in[4];
    const float* log_strength = (const float*)d_in[5];
    const float* log_tau_rec  = (const float*)d_in[6];
    const float* logit_U      = (const float*)d_in[7];
    float* out = (float*)d_out;

    _Float16* Ah = (_Float16*)d_ws;                                     // 16 MB
    _Float16* Wt = (_Float16*)((char*)d_ws + (size_t)BATCH * NPRE * 2); // 128 MB

    prep_kernel<<<(BATCH * NPRE) / (256 * 4), 256, 0, stream>>>(
        spikes, x_std, I_syn, log_tau_rec, logit_U, Ah, out);
    transpose_kernel<<<dim3(NPOST / 64, NPRE / 64), 256, 0, stream>>>(Wnm, Wt);
    gemm_kernel<<<(NPOST / BN) * (BATCH / BM) * SPLITK, 512, 0, stream>>>(
        Ah, Wt, noise, log_strength, out);
}